// Round 10
// baseline (327.753 us; speedup 1.0000x reference)
//
#include <hip/hip_runtime.h>
#include <math.h>

#define LMAX 8
#define NCOEF 45   // (LMAX+1)*(LMAX+2)/2
#define CHUNK 256  // points per chunk == blockDim
#define GRID  1024 // persistent blocks (4/CU): tight moving write front

// Native clang vector type (HIP_vector_type float4 is a class).
typedef float f4 __attribute__((ext_vector_type(4)));

struct Coefs { float c[NCOEF]; };

// One chunk of one region: compute CHUNK points' band L, stage in LDS,
// flush one dense CHUNK*(2L+1)-float run with nt f4 stores.
template<int L>
__device__ __forceinline__ void do_chunk(const float* __restrict__ R,
                                         float* __restrict__ out, int N,
                                         const Coefs& cf, long long p0,
                                         float* sm) {
    const int tid = threadIdx.x;
    int cnt = (int)((long long)N - p0);
    if (cnt > CHUNK) cnt = CHUNK;

    constexpr int W = 2 * L + 1;
    const long long region = (long long)N * (L * L) + p0 * W;
    const long long i = p0 + tid;

    if constexpr (L == 0) {                        // constant band: pure fill
        if (tid < cnt) __builtin_nontemporal_store(cf.c[0], &out[i]);
        return;
    }

    float x = 0.0f, y = 0.0f, z = 1.0f;
    if (tid < cnt) { x = R[3 * i]; y = R[3 * i + 1]; z = R[3 * i + 2]; }
    float rinv = 1.0f / sqrtf(x * x + y * y + z * z);
    x *= rinv; y *= rinv; z *= rinv;

    // A/B ladder to L, then P_L^m from P_m^m for each m (all unrolled).
    float Am[L + 1], Bm[L + 1];
    Am[0] = 1.0f; Bm[0] = 0.0f;
    #pragma unroll
    for (int m = 1; m <= L; ++m) {
        Am[m] = x * Am[m - 1] - y * Bm[m - 1];
        Bm[m] = x * Bm[m - 1] + y * Am[m - 1];
    }

    float vals[W];
    #pragma unroll
    for (int m = 0; m <= L; ++m) {
        float pmm = 1.0f;                          // (2m-1)!! at compile time
        #pragma unroll
        for (int k = 1; k < 2 * m; k += 2) pmm *= (float)k;
        float p1 = pmm, p2 = 0.0f, p = pmm;
        #pragma unroll
        for (int l = m + 1; l <= L; ++l) {
            p = (l == m + 1)
                ? (2.0f * (float)m + 1.0f) * z * p1
                : ((2.0f * (float)l - 1.0f) * z * p1 - (float)(l + m - 1) * p2)
                  * (1.0f / (float)(l - m));       // folds to constant
            p2 = p1; p1 = p;
        }
        float np = cf.c[L * (L + 1) / 2 + m] * p;
        if (m == 0) { vals[L] = np; }
        else { vals[L + m] = np * Am[m]; vals[L - m] = np * Bm[m]; }
    }

    #pragma unroll
    for (int c = 0; c < W; ++c) sm[tid * W + c] = vals[c];   // odd stride: no conflicts
    __syncthreads();                               // RAW: staging visible

    if (cnt == CHUNK && ((region & 3) == 0)) {
        f4* __restrict__ out4 = (f4*)(out + region);
        const f4* s4 = (const f4*)sm;
        #pragma unroll
        for (int t = tid; t < CHUNK * W / 4; t += 256)
            __builtin_nontemporal_store(s4[t], &out4[t]);
    } else {
        for (int t = tid; t < cnt * W; t += 256)
            out[region + t] = sm[t];
    }
    __syncthreads();                               // WAR: reads done before restage
}

template<int L>
__device__ __forceinline__ void sweep(const float* __restrict__ R,
                                      float* __restrict__ out, int N,
                                      int nchunks, const Coefs& cf, float* sm) {
    // Grid-stride: GRID blocks advance one coherent front through region L.
    for (int c = blockIdx.x; c < nchunks; c += GRID)
        do_chunk<L>(R, out, N, cf, (long long)c * CHUNK, sm);
}

__global__ __launch_bounds__(256) void sph_kernel(const float* __restrict__ R,
                                                  float* __restrict__ out,
                                                  int N, int nchunks, Coefs cf) {
    __shared__ __align__(16) float sm[CHUNK * 17];
    // Region-major: nine sequential fill-like passes. nt output stores keep
    // the 12 MB input L3-resident across all nine sweeps.
    sweep<0>(R, out, N, nchunks, cf, sm);
    sweep<1>(R, out, N, nchunks, cf, sm);
    sweep<2>(R, out, N, nchunks, cf, sm);
    sweep<3>(R, out, N, nchunks, cf, sm);
    sweep<4>(R, out, N, nchunks, cf, sm);
    sweep<5>(R, out, N, nchunks, cf, sm);
    sweep<6>(R, out, N, nchunks, cf, sm);
    sweep<7>(R, out, N, nchunks, cf, sm);
    sweep<8>(R, out, N, nchunks, cf, sm);
}

extern "C" void kernel_launch(void* const* d_in, const int* in_sizes, int n_in,
                              void* d_out, int out_size, void* d_ws, size_t ws_size,
                              hipStream_t stream) {
    const float* R = (const float*)d_in[0];
    float* out = (float*)d_out;
    int N = in_sizes[0] / 3;

    // Norms in l-outer order: idx = l*(l+1)/2 + m.
    Coefs cf;
    for (int l = 0; l <= LMAX; ++l) {
        for (int m = 0; m <= l; ++m) {
            double fr = 1.0;
            for (int k = l - m + 1; k <= l + m; ++k) fr *= (double)k;
            double norm = sqrt((double)(2 * l + 1) / (4.0 * M_PI) / fr);
            if (m > 0) norm *= sqrt(2.0);
            cf.c[l * (l + 1) / 2 + m] = (float)norm;
        }
    }

    int nchunks = (N + CHUNK - 1) / CHUNK;
    int grid = GRID < nchunks ? GRID : nchunks;
    sph_kernel<<<grid, 256, 0, stream>>>(R, out, N, nchunks, cf);
}